// Round 1
// baseline (131.120 us; speedup 1.0000x reference)
//
#include <hip/hip_runtime.h>
#include <stdint.h>

// pairs_of_pairs: fused [concat -> conv1x1+relu x3]
// B=32, C=64, S=64, CC=128, OC=256. rows = B*(S-1) = 2016, 64 positions each.
// Strategy: one block per (b,dd) row. Build 256ch x 64pos bf16 tile in LDS,
// then 3 chained 256x256 GEMM layers with mfma_f32_16x16x32_bf16,
// weights bf16 from global (L2-resident), h kept in LDS between layers.

typedef __attribute__((ext_vector_type(8))) __bf16 bf16x8;
typedef __attribute__((ext_vector_type(4))) float f32x4;
typedef __attribute__((ext_vector_type(4))) unsigned short u16x4;
typedef __attribute__((ext_vector_type(8))) unsigned short u16x8;

__device__ __forceinline__ unsigned short f2bf(float f) {
  // round-to-nearest-even fp32 -> bf16 (finite data only)
  unsigned int u = __builtin_bit_cast(unsigned int, f);
  u += 0x7FFFu + ((u >> 16) & 1u);
  return (unsigned short)(u >> 16);
}

// X_lds element index for [pos][c] bf16 tile (64 x 256), XOR-swizzled:
// byte = pos*512 + c*2 ; 16B-slot = pos*32 + c/8 ; slot ^= (pos&7).
// Breaks the 512B-row-stride bank conflict on ds_read_b128 (G4 / T2).
__device__ __forceinline__ int xaddr(int pos, int c) {
  int slot = (pos << 5) + (c >> 3);
  slot ^= (pos & 7);
  return (slot << 3) + (c & 7);
}

__global__ void wconv_kernel(const float* __restrict__ W1, const float* __restrict__ W2,
                             const float* __restrict__ W3, unsigned short* __restrict__ wb) {
  int i = (blockIdx.x * 256 + threadIdx.x) * 4;  // grid 64 -> covers 65536 per layer
  const float* Ws[3] = {W1, W2, W3};
#pragma unroll
  for (int L = 0; L < 3; ++L) {
    f32x4 a = *(const f32x4*)(Ws[L] + i);
    u16x4 p;
#pragma unroll
    for (int v = 0; v < 4; ++v) p[v] = f2bf(a[v]);
    *(u16x4*)(wb + L * 65536 + i) = p;
  }
}

__global__ __launch_bounds__(256, 2)
void fused_kernel(const float* __restrict__ x, const float* __restrict__ xc,
                  const unsigned short* __restrict__ wb,
                  const float* __restrict__ b1, const float* __restrict__ b2,
                  const float* __restrict__ b3, float* __restrict__ out) {
  __shared__ __align__(16) unsigned short X[64 * 256];  // 32 KB, [pos][c] swizzled bf16
  __shared__ __align__(16) float stage[64 * 64];        // 16 KB, [c][i] fp32 staging

  const int r = blockIdx.x;       // 0..2015
  const int b = r / 63;
  const int dd = r % 63;
  const int d = dd + 1;
  const int tid = threadIdx.x;
  const int lane = tid & 63;
  const int g16 = lane >> 4;      // lane group 0..3
  const int l16 = lane & 15;
  const int wv = tid >> 6;        // wave 0..3

  // ---------------- build layer-0 input tile ----------------
  // chunk 0: xc ch 0..63 | chunk 1: xc ch 64..127 | chunk 2: x (x_rep) |
  // chunk 3: rolled x (reuses chunk-2 staging, roll applied at read)
  for (int chunk = 0; chunk < 4; ++chunk) {
    if (chunk < 3) {
      // stage A: 64 rows x 64 floats, coalesced along i
#pragma unroll
      for (int it = 0; it < 4; ++it) {
        int u = it * 256 + tid;        // 0..1023
        int cc = u >> 4;               // row 0..63
        int i4 = (u & 15) << 2;        // 0..60 step 4
        const float* src;
        if (chunk < 2) src = xc + (((b * 128 + chunk * 64 + cc) * 63) + dd) * 64 + i4;
        else           src = x + (b * 64 + cc) * 64 + i4;
        *(f32x4*)&stage[cc * 64 + i4] = *(const f32x4*)src;
      }
    }
    __syncthreads();
    // stage B: transpose+convert into X (16B swizzled ds_write per lane)
    {
      int cbase = chunk * 64;
#pragma unroll
      for (int it = 0; it < 2; ++it) {
        int u = it * 256 + tid;        // 0..511
        int i = u & 63;                // position
        int c0 = (u >> 6) << 3;        // 0,8,...,56
        int ieff = (chunk == 3) ? ((i - d + 64) & 63) : i;
        u16x8 p;
#pragma unroll
        for (int j = 0; j < 8; ++j) p[j] = f2bf(stage[(c0 + j) * 64 + ieff]);
        *(u16x8*)&X[xaddr(i, cbase + c0)] = p;
      }
    }
    __syncthreads();
  }

  // ---------------- 3 fused conv1x1+relu layers ----------------
  for (int layer = 0; layer < 3; ++layer) {
    const unsigned short* wl = wb + layer * 65536;
    const float* bias = (layer == 0) ? b1 : (layer == 1) ? b2 : b3;

    f32x4 acc[4][4] = {};              // [mf][nf], wave tile = 64 o x 64 pos
    const int ow = wv * 64;

    for (int kk = 0; kk < 8; ++kk) {
      int kb = kk * 32 + g16 * 8;      // this lane-group's k-base (8 contiguous k)
      bf16x8 bfr[4];
#pragma unroll
      for (int nf = 0; nf < 4; ++nf)
        bfr[nf] = __builtin_bit_cast(bf16x8, *(const u16x8*)&X[xaddr(nf * 16 + l16, kb)]);
#pragma unroll
      for (int mf = 0; mf < 4; ++mf) {
        bf16x8 afr = __builtin_bit_cast(
            bf16x8, *(const u16x8*)(wl + (ow + mf * 16 + l16) * 256 + kb));
#pragma unroll
        for (int nf = 0; nf < 4; ++nf)
          acc[mf][nf] = __builtin_amdgcn_mfma_f32_16x16x32_bf16(afr, bfr[nf], acc[mf][nf], 0, 0, 0);
      }
    }
    __syncthreads();  // all waves done reading X before it is overwritten

    if (layer < 2) {
      // bias + relu -> bf16 back into X  (D frag: pos = l16, o = g16*4+v)
#pragma unroll
      for (int mf = 0; mf < 4; ++mf) {
        int o0 = ow + mf * 16 + g16 * 4;
        f32x4 bv = *(const f32x4*)(bias + o0);
#pragma unroll
        for (int nf = 0; nf < 4; ++nf) {
          int pos = nf * 16 + l16;
          u16x4 p;
#pragma unroll
          for (int v = 0; v < 4; ++v)
            p[v] = f2bf(fmaxf(acc[mf][nf][v] + bv[v], 0.f));
          *(u16x4*)&X[xaddr(pos, o0)] = p;
        }
      }
      __syncthreads();
    } else {
      // final layer: bias + relu -> fp32 global store
#pragma unroll
      for (int mf = 0; mf < 4; ++mf) {
        int o0 = ow + mf * 16 + g16 * 4;
        f32x4 bv = *(const f32x4*)(bias + o0);
#pragma unroll
        for (int nf = 0; nf < 4; ++nf) {
          int pos = nf * 16 + l16;
#pragma unroll
          for (int v = 0; v < 4; ++v) {
            float val = fmaxf(acc[mf][nf][v] + bv[v], 0.f);
            out[((b * 256 + o0 + v) * 63 + dd) * 64 + pos] = val;
          }
        }
      }
    }
  }
}

extern "C" void kernel_launch(void* const* d_in, const int* in_sizes, int n_in,
                              void* d_out, int out_size, void* d_ws, size_t ws_size,
                              hipStream_t stream) {
  const float* x  = (const float*)d_in[0];
  const float* xc = (const float*)d_in[1];
  const float* W1 = (const float*)d_in[2];
  const float* b1 = (const float*)d_in[3];
  const float* W2 = (const float*)d_in[4];
  const float* b2 = (const float*)d_in[5];
  const float* W3 = (const float*)d_in[6];
  const float* b3 = (const float*)d_in[7];
  float* out = (float*)d_out;
  unsigned short* wb = (unsigned short*)d_ws;  // 3 x 256 x 256 bf16 = 384 KB

  wconv_kernel<<<64, 256, 0, stream>>>(W1, W2, W3, wb);
  fused_kernel<<<2016, 256, 0, stream>>>(x, xc, wb, b1, b2, b3, out);
}